// Round 25
// baseline (81.502 us; speedup 1.0000x reference)
//
#include <hip/hip_runtime.h>

typedef __attribute__((ext_vector_type(8))) _Float16 f16x8;
typedef __attribute__((ext_vector_type(4))) float f32x4;
typedef __attribute__((ext_vector_type(4))) _Float16 h4;
typedef __attribute__((ext_vector_type(2))) __fp16 hw2;
typedef __attribute__((ext_vector_type(2))) float v2f;

#define IMG 512
#define OUT_N 502
#define NPLANE 48
#define NBAND 32             // 16 output rows per band
#define NCG 2                // 256-output-col groups
#define NBLK (NCG * NBAND * NPLANE)   // 3072 blocks
#define NCOL 256
#define HP 40                // hlds row pitch (fp16): 32 rows + 8 pad
#define C1c 0.0001f
#define C2c 0.0004f

union H8u { hw2 p[4]; f16x8 v; };
union H4u { hw2 p[2]; h4 v; };

// scalar ssim (edge band only)
__device__ __forceinline__ float ssim_px(float mx, float my, float P, float M) {
    float A = mx*mx, B = my*my, mxy = mx*my;
    float sumsq = 0.5f*(P+M) - A - B;
    float sxy   = 0.25f*(P-M) - mxy;
    float num = (2.f*mxy + C1c) * (2.f*sxy + C2c);
    float den = (A + B + C1c) * (sumsq + C2c);
    return num * __builtin_amdgcn_rcpf(den);
}

// packed-pair ssim: v_pk_*_f32 chain, scalar rcp x2
__device__ __forceinline__ float ssim_px2(v2f mx, v2f my, v2f P, v2f M) {
    v2f A = mx*mx, B = my*my, mxy = mx*my;
    v2f sumsq = 0.5f*(P+M) - A - B;
    v2f sxy   = 0.25f*(P-M) - mxy;
    v2f num = (2.f*mxy + C1c) * (2.f*sxy + C2c);
    v2f den = (A + B + C1c) * (sumsq + C2c);
    return num.x * __builtin_amdgcn_rcpf(den.x)
         + num.y * __builtin_amdgcn_rcpf(den.y);
}

// H-FIRST, R23-scale blocks. Block = 16 out rows x 256 out cols, 512 thr
// (8 waves, 8 px/thread -- same amortization as the 31us V-first kernel).
//  H: D = Data(16x32) x Band(32x16), k = image COLS -> lane's 8 k-elements
//     are 8 consecutive floats -> 2 dwordx4 per source (16 dwordx4/thread
//     total vs 64 scalar dwords in V-first). 32 positions (2 row-chunks x
//     16 col-tiles), 4/wave. D = [img row 4kg+m][out col fi] -> packed
//     ds_write_b64 to hlds[f][col][row].
//  V: D2 = Band(16x32) x Hdata(32x16), B-frag = one b128 from
//     hlds[f][colL][kB]; 16 col-tiles, 2/wave. Same epilogue as R20-R23.
//  band_f = g[kB+q-fi] serves all operand roles (verified R17/R19/R24).
//  Clamp correctness: V weights vanish k>=26; H col-clamp only hits
//  zero-weight taps. LDS 80KB -> 2 blocks/CU. Bijective XCD swizzle
//  (3072%8==0) keeps adjacent bands (10 halo rows) on one XCD's L2 (R23's
//  +27% lever).
__global__ __launch_bounds__(512, 2) void ssim_hf(
    const float* __restrict__ in, const float* __restrict__ tgt,
    const float* __restrict__ w, float* __restrict__ partial)
{
    __shared__ __attribute__((aligned(16))) _Float16 hlds[4][NCOL][HP];
    __shared__ float g1s[16];
    __shared__ float red[8];

    const int tid  = threadIdx.x;
    const int lane = tid & 63;
    const int wv   = tid >> 6;           // wave 0..7
    const int f    = blockIdx.x;
    const int s    = ((f & 7) * (NBLK / 8)) + (f >> 3);   // bijective
    const int cg    = s & (NCG - 1);
    const int band  = (s >> 1) & (NBAND - 1);
    const int plane = s >> 6;
    const int r0 = band * 16;
    const int c0 = cg * NCOL;
    const bool edge = (r0 + 16 > OUT_N);  // block-uniform (band 31)
    const float* __restrict__ ip = in  + (size_t)plane * (IMG*IMG);
    const float* __restrict__ tp = tgt + (size_t)plane * (IMG*IMG);

    const int fi = lane & 15;
    const int kg = lane >> 4;
    const int kB = kg * 8;

    // 4 H positions per wave: p = 4*wv + i; chunk = p>>4 (row), tile = p&15.
    int rowp[4], cbp[4], tilep[4], chkp[4];
    #pragma unroll
    for (int i = 0; i < 4; ++i) {
        const int p = 4*wv + i;
        chkp[i]  = p >> 4;
        tilep[i] = p & 15;
        rowp[i] = min(r0 + 16*chkp[i] + fi, IMG - 1);
        cbp[i]  = min(c0 + 16*tilep[i] + kB, IMG - 8);
    }

    // Batched vector loads (16 dwordx4/thread) before the preamble barrier.
    f32x4 xa[4], xb[4], ya[4], yb[4];
    #pragma unroll
    for (int i = 0; i < 4; ++i) {
        const float* ipr = ip + rowp[i]*IMG + cbp[i];
        const float* tpr = tp + rowp[i]*IMG + cbp[i];
        xa[i] = *(const f32x4*)(ipr);
        xb[i] = *(const f32x4*)(ipr + 4);
        ya[i] = *(const f32x4*)(tpr);
        yb[i] = *(const f32x4*)(tpr + 4);
    }

    // 1D factor = row sums of the 2D kernel (exact: w2d = outer(g,g), sum = 1)
    if (tid < 11) {
        float ws_ = 0.f;
        #pragma unroll
        for (int j = 0; j < 11; ++j) ws_ += w[tid*11 + j];
        g1s[tid] = ws_;
    }
    __syncthreads();
    float g[11];
    #pragma unroll
    for (int j = 0; j < 11; ++j)
        g[j] = __int_as_float(__builtin_amdgcn_readfirstlane(__float_as_int(g1s[j])));

    // Banded weight fragment: band_f[q] = g[kB+q - fi] (zero outside 0..10).
    f16x8 band_f;
    #pragma unroll
    for (int q = 0; q < 8; ++q) {
        float wq = 0.f;
        #pragma unroll
        for (int j = 0; j <= 10; ++j)
            wq = (kB + q - fi == j) ? g[j] : wq;
        band_f[q] = (_Float16)wq;
    }

    const f32x4 z = {0.f, 0.f, 0.f, 0.f};

#define HSTORE(F, D) \
    { H4u u_; \
      u_.p[0] = __builtin_amdgcn_cvt_pkrtz((D)[0], (D)[1]); \
      u_.p[1] = __builtin_amdgcn_cvt_pkrtz((D)[2], (D)[3]); \
      *reinterpret_cast<h4*>(&hlds[F][colL][rowL]) = u_.v; }

    // H phase: 4 positions per wave.
    #pragma unroll
    for (int i = 0; i < 4; ++i) {
        H8u ux, uy;
        ux.p[0] = __builtin_amdgcn_cvt_pkrtz(xa[i][0], xa[i][1]);
        ux.p[1] = __builtin_amdgcn_cvt_pkrtz(xa[i][2], xa[i][3]);
        ux.p[2] = __builtin_amdgcn_cvt_pkrtz(xb[i][0], xb[i][1]);
        ux.p[3] = __builtin_amdgcn_cvt_pkrtz(xb[i][2], xb[i][3]);
        uy.p[0] = __builtin_amdgcn_cvt_pkrtz(ya[i][0], ya[i][1]);
        uy.p[1] = __builtin_amdgcn_cvt_pkrtz(ya[i][2], ya[i][3]);
        uy.p[2] = __builtin_amdgcn_cvt_pkrtz(yb[i][0], yb[i][1]);
        uy.p[3] = __builtin_amdgcn_cvt_pkrtz(yb[i][2], yb[i][3]);
        f16x8 fX = ux.v, fY = uy.v;
        f16x8 fS = fX + fY, fD = fX - fY;
        f16x8 fP = fS * fS, fM = fD * fD;
        f32x4 dX = __builtin_amdgcn_mfma_f32_16x16x32_f16(fX, band_f, z, 0, 0, 0);
        f32x4 dY = __builtin_amdgcn_mfma_f32_16x16x32_f16(fY, band_f, z, 0, 0, 0);
        f32x4 dP = __builtin_amdgcn_mfma_f32_16x16x32_f16(fP, band_f, z, 0, 0, 0);
        f32x4 dM = __builtin_amdgcn_mfma_f32_16x16x32_f16(fM, band_f, z, 0, 0, 0);
        const int colL = 16*tilep[i] + fi;   // block-local out col
        const int rowL = 16*chkp[i] + 4*kg;  // block-local img row
        HSTORE(0, dX) HSTORE(1, dY) HSTORE(2, dP) HSTORE(3, dM)
    }

    __syncthreads();

    // ---- V phase: 2 col-tiles per wave ----
    float acc = 0.f;
    #pragma unroll
    for (int j2 = 0; j2 < 2; ++j2) {
        const int colL = 16*(2*wv + j2) + fi;
        f16x8 bX = *reinterpret_cast<const f16x8*>(&hlds[0][colL][kB]);
        f16x8 bY = *reinterpret_cast<const f16x8*>(&hlds[1][colL][kB]);
        f16x8 bP = *reinterpret_cast<const f16x8*>(&hlds[2][colL][kB]);
        f16x8 bM = *reinterpret_cast<const f16x8*>(&hlds[3][colL][kB]);
        f32x4 dX = __builtin_amdgcn_mfma_f32_16x16x32_f16(band_f, bX, z, 0, 0, 0);
        f32x4 dY = __builtin_amdgcn_mfma_f32_16x16x32_f16(band_f, bY, z, 0, 0, 0);
        f32x4 dP = __builtin_amdgcn_mfma_f32_16x16x32_f16(band_f, bP, z, 0, 0, 0);
        f32x4 dM = __builtin_amdgcn_mfma_f32_16x16x32_f16(band_f, bM, z, 0, 0, 0);
        const int oc = c0 + colL;
        if (oc < OUT_N) {
            if (!edge) {
                v2f mx0 = {dX[0], dX[1]}, my0 = {dY[0], dY[1]};
                v2f P0  = {dP[0], dP[1]}, M0  = {dM[0], dM[1]};
                v2f mx1 = {dX[2], dX[3]}, my1 = {dY[2], dY[3]};
                v2f P1  = {dP[2], dP[3]}, M1  = {dM[2], dM[3]};
                acc += ssim_px2(mx0, my0, P0, M0);
                acc += ssim_px2(mx1, my1, P1, M1);
            } else {
                #pragma unroll
                for (int m = 0; m < 4; ++m) {
                    const int oy = r0 + kg*4 + m;
                    if (oy < OUT_N)
                        acc += ssim_px(dX[m], dY[m], dP[m], dM[m]);
                }
            }
        }
    }

    // block reduction: wave shuffle, then 8 wave-partials through LDS
    #pragma unroll
    for (int off = 32; off > 0; off >>= 1)
        acc += __shfl_down(acc, off, 64);
    if (lane == 0) red[wv] = acc;
    __syncthreads();
    if (tid == 0) {
        float t = 0.f;
        #pragma unroll
        for (int i = 0; i < 8; ++i) t += red[i];
        partial[s] = t;
    }
}

// Deterministic final reduction: fixed traversal, double accumulation.
__global__ __launch_bounds__(256) void ssim_final(
    const float* __restrict__ partial, int n, float* __restrict__ out)
{
    __shared__ double red[256];
    double s = 0.0;
    for (int i = threadIdx.x; i < n; i += 256) s += (double)partial[i];
    red[threadIdx.x] = s;
    __syncthreads();
    for (int off = 128; off > 0; off >>= 1) {
        if (threadIdx.x < off) red[threadIdx.x] += red[threadIdx.x + off];
        __syncthreads();
    }
    if (threadIdx.x == 0) out[0] = (float)(1.0 - red[0] / (double)NPLANE);
}

extern "C" void kernel_launch(void* const* d_in, const int* in_sizes, int n_in,
                              void* d_out, int out_size, void* d_ws, size_t ws_size,
                              hipStream_t stream) {
    const float* in  = (const float*)d_in[0];
    const float* tgt = (const float*)d_in[1];
    const float* wt  = (const float*)d_in[2];
    float* out  = (float*)d_out;
    float* part = (float*)d_ws;

    ssim_hf<<<dim3(NBLK), 512, 0, stream>>>(in, tgt, wt, part);
    ssim_final<<<1, 256, 0, stream>>>(part, NBLK, out);
}

// Round 26
// 57.600 us; speedup vs baseline: 1.4150x; 1.4150x over previous
//
#include <hip/hip_runtime.h>

typedef __attribute__((ext_vector_type(8))) _Float16 f16x8;
typedef __attribute__((ext_vector_type(4))) float f32x4;
typedef __attribute__((ext_vector_type(4))) _Float16 h4;
typedef __attribute__((ext_vector_type(2))) __fp16 hw2;
typedef __attribute__((ext_vector_type(2))) float v2f;

#define IMG 512
#define OUT_N 502
#define NPLANE 48
#define NBAND 32             // 16 output rows per band
#define NCG 2                // 256-output-col groups
#define NBLK (NCG * NBAND * NPLANE)   // 3072 blocks
#define NCOL 256
#define HP 36                // hlds row pitch (fp16): 72B col stride ->
                             // 18-dword stride: H-stores conflict-free,
                             // V-reads ~4-way; total LDS 72KB -> 2 blocks/CU
#define C1c 0.0001f
#define C2c 0.0004f

union H8u { hw2 p[4]; f16x8 v; };
union H4u { hw2 p[2]; h4 v; };
union H8r { h4 h[2]; f16x8 v; };

// scalar ssim (edge band only)
__device__ __forceinline__ float ssim_px(float mx, float my, float P, float M) {
    float A = mx*mx, B = my*my, mxy = mx*my;
    float sumsq = 0.5f*(P+M) - A - B;
    float sxy   = 0.25f*(P-M) - mxy;
    float num = (2.f*mxy + C1c) * (2.f*sxy + C2c);
    float den = (A + B + C1c) * (sumsq + C2c);
    return num * __builtin_amdgcn_rcpf(den);
}

// packed-pair ssim: v_pk_*_f32 chain, scalar rcp x2
__device__ __forceinline__ float ssim_px2(v2f mx, v2f my, v2f P, v2f M) {
    v2f A = mx*mx, B = my*my, mxy = mx*my;
    v2f sumsq = 0.5f*(P+M) - A - B;
    v2f sxy   = 0.25f*(P-M) - mxy;
    v2f num = (2.f*mxy + C1c) * (2.f*sxy + C2c);
    v2f den = (A + B + C1c) * (sumsq + C2c);
    return num.x * __builtin_amdgcn_rcpf(den.x)
         + num.y * __builtin_amdgcn_rcpf(den.y);
}

// H-FIRST, R23-scale blocks, LDS geometry fixed (R25's 82KB > 80KB dropped
// occupancy to 1 block/CU -- THE regression cause; HP 40->36 restores 2).
// Block = 16 out rows x 256 out cols, 512 thr (8 waves, 8 px/thread).
//  H: D = Data(16x32) x Band(32x16), k = image COLS -> lane's 8 k-elements
//     are 8 consecutive floats -> 2 dwordx4 per source (16 dwordx4/thread
//     total vs 64 scalar dwords in V-first). 32 positions, 4/wave.
//     D = [img row 4kg+m][out col fi] -> packed ds_write_b64 (8B-aligned:
//     72 = 8*9) to hlds[f][col][row].
//  V: D2 = Band(16x32) x Hdata(32x16), B-frag = two ds_read_b64 from
//     hlds[f][colL][kB] (+4); 16 col-tiles, 2/wave. Epilogue as R20-R23.
//  band_f = g[kB+q-fi] serves all operand roles (verified R17/R19/R24).
//  Clamps: V weights vanish k>=26; H col-clamp only hits zero-weight taps.
//  Bijective XCD swizzle (3072%8==0): each XCD owns 6 contiguous planes,
//  adjacent bands share 10 halo rows in its L2 (R23's +27% lever).
__global__ __launch_bounds__(512, 2) void ssim_hf(
    const float* __restrict__ in, const float* __restrict__ tgt,
    const float* __restrict__ w, float* __restrict__ partial)
{
    __shared__ __attribute__((aligned(16))) _Float16 hlds[4][NCOL][HP];
    __shared__ float g1s[16];
    __shared__ float red[8];

    const int tid  = threadIdx.x;
    const int lane = tid & 63;
    const int wv   = tid >> 6;           // wave 0..7
    const int f    = blockIdx.x;
    const int s    = ((f & 7) * (NBLK / 8)) + (f >> 3);   // bijective
    const int cg    = s & (NCG - 1);
    const int band  = (s >> 1) & (NBAND - 1);
    const int plane = s >> 6;
    const int r0 = band * 16;
    const int c0 = cg * NCOL;
    const bool edge = (r0 + 16 > OUT_N);  // block-uniform (band 31)
    const float* __restrict__ ip = in  + (size_t)plane * (IMG*IMG);
    const float* __restrict__ tp = tgt + (size_t)plane * (IMG*IMG);

    const int fi = lane & 15;
    const int kg = lane >> 4;
    const int kB = kg * 8;

    // 4 H positions per wave: p = 4*wv + i; chunk = p>>4 (row), tile = p&15.
    int rowp[4], cbp[4], tilep[4], chkp[4];
    #pragma unroll
    for (int i = 0; i < 4; ++i) {
        const int p = 4*wv + i;
        chkp[i]  = p >> 4;
        tilep[i] = p & 15;
        rowp[i] = min(r0 + 16*chkp[i] + fi, IMG - 1);
        cbp[i]  = min(c0 + 16*tilep[i] + kB, IMG - 8);
    }

    // Batched vector loads (16 dwordx4/thread) before the preamble barrier.
    f32x4 xa[4], xb[4], ya[4], yb[4];
    #pragma unroll
    for (int i = 0; i < 4; ++i) {
        const float* ipr = ip + rowp[i]*IMG + cbp[i];
        const float* tpr = tp + rowp[i]*IMG + cbp[i];
        xa[i] = *(const f32x4*)(ipr);
        xb[i] = *(const f32x4*)(ipr + 4);
        ya[i] = *(const f32x4*)(tpr);
        yb[i] = *(const f32x4*)(tpr + 4);
    }

    // 1D factor = row sums of the 2D kernel (exact: w2d = outer(g,g), sum = 1)
    if (tid < 11) {
        float ws_ = 0.f;
        #pragma unroll
        for (int j = 0; j < 11; ++j) ws_ += w[tid*11 + j];
        g1s[tid] = ws_;
    }
    __syncthreads();
    float g[11];
    #pragma unroll
    for (int j = 0; j < 11; ++j)
        g[j] = __int_as_float(__builtin_amdgcn_readfirstlane(__float_as_int(g1s[j])));

    // Banded weight fragment: band_f[q] = g[kB+q - fi] (zero outside 0..10).
    f16x8 band_f;
    #pragma unroll
    for (int q = 0; q < 8; ++q) {
        float wq = 0.f;
        #pragma unroll
        for (int j = 0; j <= 10; ++j)
            wq = (kB + q - fi == j) ? g[j] : wq;
        band_f[q] = (_Float16)wq;
    }

    const f32x4 z = {0.f, 0.f, 0.f, 0.f};

#define HSTORE(F, D) \
    { H4u u_; \
      u_.p[0] = __builtin_amdgcn_cvt_pkrtz((D)[0], (D)[1]); \
      u_.p[1] = __builtin_amdgcn_cvt_pkrtz((D)[2], (D)[3]); \
      *reinterpret_cast<h4*>(&hlds[F][colL][rowL]) = u_.v; }

    // H phase: 4 positions per wave.
    #pragma unroll
    for (int i = 0; i < 4; ++i) {
        H8u ux, uy;
        ux.p[0] = __builtin_amdgcn_cvt_pkrtz(xa[i][0], xa[i][1]);
        ux.p[1] = __builtin_amdgcn_cvt_pkrtz(xa[i][2], xa[i][3]);
        ux.p[2] = __builtin_amdgcn_cvt_pkrtz(xb[i][0], xb[i][1]);
        ux.p[3] = __builtin_amdgcn_cvt_pkrtz(xb[i][2], xb[i][3]);
        uy.p[0] = __builtin_amdgcn_cvt_pkrtz(ya[i][0], ya[i][1]);
        uy.p[1] = __builtin_amdgcn_cvt_pkrtz(ya[i][2], ya[i][3]);
        uy.p[2] = __builtin_amdgcn_cvt_pkrtz(yb[i][0], yb[i][1]);
        uy.p[3] = __builtin_amdgcn_cvt_pkrtz(yb[i][2], yb[i][3]);
        f16x8 fX = ux.v, fY = uy.v;
        f16x8 fS = fX + fY, fD = fX - fY;
        f16x8 fP = fS * fS, fM = fD * fD;
        f32x4 dX = __builtin_amdgcn_mfma_f32_16x16x32_f16(fX, band_f, z, 0, 0, 0);
        f32x4 dY = __builtin_amdgcn_mfma_f32_16x16x32_f16(fY, band_f, z, 0, 0, 0);
        f32x4 dP = __builtin_amdgcn_mfma_f32_16x16x32_f16(fP, band_f, z, 0, 0, 0);
        f32x4 dM = __builtin_amdgcn_mfma_f32_16x16x32_f16(fM, band_f, z, 0, 0, 0);
        const int colL = 16*tilep[i] + fi;   // block-local out col
        const int rowL = 16*chkp[i] + 4*kg;  // block-local img row
        HSTORE(0, dX) HSTORE(1, dY) HSTORE(2, dP) HSTORE(3, dM)
    }

    __syncthreads();

#define VREAD(F, DST) \
    { H8r u_; \
      u_.h[0] = *reinterpret_cast<const h4*>(&hlds[F][colL][kB]); \
      u_.h[1] = *reinterpret_cast<const h4*>(&hlds[F][colL][kB + 4]); \
      DST = u_.v; }

    // ---- V phase: 2 col-tiles per wave ----
    float acc = 0.f;
    #pragma unroll
    for (int j2 = 0; j2 < 2; ++j2) {
        const int colL = 16*(2*wv + j2) + fi;
        f16x8 bX, bY, bP, bM;
        VREAD(0, bX) VREAD(1, bY) VREAD(2, bP) VREAD(3, bM)
        f32x4 dX = __builtin_amdgcn_mfma_f32_16x16x32_f16(band_f, bX, z, 0, 0, 0);
        f32x4 dY = __builtin_amdgcn_mfma_f32_16x16x32_f16(band_f, bY, z, 0, 0, 0);
        f32x4 dP = __builtin_amdgcn_mfma_f32_16x16x32_f16(band_f, bP, z, 0, 0, 0);
        f32x4 dM = __builtin_amdgcn_mfma_f32_16x16x32_f16(band_f, bM, z, 0, 0, 0);
        const int oc = c0 + colL;
        if (oc < OUT_N) {
            if (!edge) {
                v2f mx0 = {dX[0], dX[1]}, my0 = {dY[0], dY[1]};
                v2f P0  = {dP[0], dP[1]}, M0  = {dM[0], dM[1]};
                v2f mx1 = {dX[2], dX[3]}, my1 = {dY[2], dY[3]};
                v2f P1  = {dP[2], dP[3]}, M1  = {dM[2], dM[3]};
                acc += ssim_px2(mx0, my0, P0, M0);
                acc += ssim_px2(mx1, my1, P1, M1);
            } else {
                #pragma unroll
                for (int m = 0; m < 4; ++m) {
                    const int oy = r0 + kg*4 + m;
                    if (oy < OUT_N)
                        acc += ssim_px(dX[m], dY[m], dP[m], dM[m]);
                }
            }
        }
    }

    // block reduction: wave shuffle, then 8 wave-partials through LDS
    #pragma unroll
    for (int off = 32; off > 0; off >>= 1)
        acc += __shfl_down(acc, off, 64);
    if (lane == 0) red[wv] = acc;
    __syncthreads();
    if (tid == 0) {
        float t = 0.f;
        #pragma unroll
        for (int i = 0; i < 8; ++i) t += red[i];
        partial[s] = t;
    }
}

// Deterministic final reduction: fixed traversal, double accumulation.
__global__ __launch_bounds__(256) void ssim_final(
    const float* __restrict__ partial, int n, float* __restrict__ out)
{
    __shared__ double red[256];
    double s = 0.0;
    for (int i = threadIdx.x; i < n; i += 256) s += (double)partial[i];
    red[threadIdx.x] = s;
    __syncthreads();
    for (int off = 128; off > 0; off >>= 1) {
        if (threadIdx.x < off) red[threadIdx.x] += red[threadIdx.x + off];
        __syncthreads();
    }
    if (threadIdx.x == 0) out[0] = (float)(1.0 - red[0] / (double)NPLANE);
}

extern "C" void kernel_launch(void* const* d_in, const int* in_sizes, int n_in,
                              void* d_out, int out_size, void* d_ws, size_t ws_size,
                              hipStream_t stream) {
    const float* in  = (const float*)d_in[0];
    const float* tgt = (const float*)d_in[1];
    const float* wt  = (const float*)d_in[2];
    float* out  = (float*)d_out;
    float* part = (float*)d_ws;

    ssim_hf<<<dim3(NBLK), 512, 0, stream>>>(in, tgt, wt, part);
    ssim_final<<<1, 256, 0, stream>>>(part, NBLK, out);
}

// Round 27
// 30.659 us; speedup vs baseline: 2.6584x; 1.8787x over previous
//
#include <hip/hip_runtime.h>

typedef __attribute__((ext_vector_type(8))) _Float16 f16x8;
typedef __attribute__((ext_vector_type(4))) float f32x4;
typedef __attribute__((ext_vector_type(4))) _Float16 h4;
typedef __attribute__((ext_vector_type(2))) __fp16 hw2;
typedef __attribute__((ext_vector_type(2))) float v2f;

#define IMG 512
#define OUT_N 502
#define NPLANE 48
#define NBAND 32             // 16 output rows per band
#define NBLK (NBAND * NPLANE)
#define VP 520               // LDS pitch (fp16): 512 + 8 pad (keeps b128 align)
#define C1c 0.0001f
#define C2c 0.0004f

union H8u { hw2 p[4]; f16x8 v; };
union H4u { hw2 p[2]; h4 v; };

// scalar ssim (edge band only)
__device__ __forceinline__ float ssim_px(float mx, float my, float P, float M) {
    float A = mx*mx, B = my*my, mxy = mx*my;
    float sumsq = 0.5f*(P+M) - A - B;
    float sxy   = 0.25f*(P-M) - mxy;
    float num = (2.f*mxy + C1c) * (2.f*sxy + C2c);
    float den = (A + B + C1c) * (sumsq + C2c);
    return num * __builtin_amdgcn_rcpf(den);
}

// packed-pair ssim: v_pk_*_f32 chain, scalar rcp x2
__device__ __forceinline__ float ssim_px2(v2f mx, v2f my, v2f P, v2f M) {
    v2f A = mx*mx, B = my*my, mxy = mx*my;
    v2f sumsq = 0.5f*(P+M) - A - B;
    v2f sxy   = 0.25f*(P-M) - mxy;
    v2f num = (2.f*mxy + C1c) * (2.f*sxy + C2c);
    v2f den = (A + B + C1c) * (sumsq + C2c);
    return num.x * __builtin_amdgcn_rcpf(den.x)
         + num.y * __builtin_amdgcn_rcpf(den.y);
}

// Block = one 16-row output band, 512 threads (8 waves). Both blurs are banded
// matmuls on the matrix pipe (layouts verified absmax 0.0 in R19):
//   V: D = Data(16x32) x Band(32x16) -> lane holds out-row fi, 4 consecutive
//      cols -> one packed ds_write_b64 per field.
//   H: D = Vdata(16x32) x Band(32x16), A-frag = one ds_read_b128 per field.
// Key levers (measured): banded-MFMA offload (+21%), packed f16/f32 math
// (+3%), bijective XCD swizzle (+27%: FETCH 110->49MB, halo re-reads become
// same-XCD L2 hits), early V-loads hidden under the w-preamble.
// H-first restructure (vectorized loads) tried 3x: strictly worse -- V-first
// scalar loads are already latency-hidden at this residency.
__global__ __launch_bounds__(512, 2) void ssim_band(
    const float* __restrict__ in, const float* __restrict__ tgt,
    const float* __restrict__ w, float* __restrict__ partial)
{
    __shared__ __attribute__((aligned(16))) _Float16 vlds[4][16][VP];
    __shared__ float g1s[16];
    __shared__ float red[8];

    const int tid   = threadIdx.x;
    const int lane  = tid & 63;
    const int wv    = tid >> 6;          // wave id 0..7
    // XCD-chunked bijective swizzle (HW dispatches flat ids round-robin
    // across 8 XCDs; 1536 % 8 == 0 so this is a bijection).
    const int f     = blockIdx.x;
    const int s     = ((f & 7) * (NBLK / 8)) + (f >> 3);
    const int band  = s & (NBAND - 1);
    const int plane = s >> 5;
    const int r0 = band * 16;
    const bool edge = (r0 + 16 > OUT_N);          // block-uniform (band 31)
    const float* __restrict__ ip = in  + (size_t)plane * (IMG*IMG);
    const float* __restrict__ tp = tgt + (size_t)plane * (IMG*IMG);

    const int fi = lane & 15;            // A-row / B-col / D-col index
    const int kg = lane >> 4;            // k-group (0..3)
    const int kB = kg * 8;               // k base for this lane

    // Hoisted V-load indices: row r0+kB+q (clamped; k>=26 weights are zero so
    // clamped garbage contributes 0), col base wv*64 + fi.
    int idx[8];
    #pragma unroll
    for (int q = 0; q < 8; ++q) {
        const int rr = min(r0 + kB + q, IMG - 1);
        idx[q] = rr * IMG + wv * 64 + fi;
    }

#define VLOAD(T, XS, YS) \
    { _Pragma("unroll") \
      for (int q = 0; q < 8; ++q) { \
          XS[q] = ip[idx[q] + 16*(T)]; \
          YS[q] = tp[idx[q] + 16*(T)]; \
      } }

    // Early issue: tiles 0 and 1 load under the w-preamble + barrier below.
    float xA[8], yA[8], xB[8], yB[8];
    VLOAD(0, xA, yA)
    VLOAD(1, xB, yB)

    // 1D factor = row sums of the 2D kernel (exact: w2d = outer(g,g), sum = 1)
    if (tid < 11) {
        float ws_ = 0.f;
        #pragma unroll
        for (int j = 0; j < 11; ++j) ws_ += w[tid*11 + j];
        g1s[tid] = ws_;
    }
    __syncthreads();
    float g[11];
    #pragma unroll
    for (int j = 0; j < 11; ++j)
        g[j] = __int_as_float(__builtin_amdgcn_readfirstlane(__float_as_int(g1s[j])));

    // Banded weight fragment: band_f[q] = g[kB+q - fi] (zero outside 0..10).
    f16x8 band_f;
    #pragma unroll
    for (int q = 0; q < 8; ++q) {
        float wq = 0.f;
        #pragma unroll
        for (int j = 0; j <= 10; ++j)
            wq = (kB + q - fi == j) ? g[j] : wq;
        band_f[q] = (_Float16)wq;
    }

    float acc = 0.f;
    const f32x4 z = {0.f, 0.f, 0.f, 0.f};

#define VSTORE(F, D) \
    { H4u u_; \
      u_.p[0] = __builtin_amdgcn_cvt_pkrtz((D)[0], (D)[1]); \
      u_.p[1] = __builtin_amdgcn_cvt_pkrtz((D)[2], (D)[3]); \
      *reinterpret_cast<h4*>(&vlds[F][fi][cb_]) = u_.v; }

#define VPROC(T, XS, YS) \
    { H8u ux, uy; \
      ux.p[0] = __builtin_amdgcn_cvt_pkrtz(XS[0], XS[1]); \
      ux.p[1] = __builtin_amdgcn_cvt_pkrtz(XS[2], XS[3]); \
      ux.p[2] = __builtin_amdgcn_cvt_pkrtz(XS[4], XS[5]); \
      ux.p[3] = __builtin_amdgcn_cvt_pkrtz(XS[6], XS[7]); \
      uy.p[0] = __builtin_amdgcn_cvt_pkrtz(YS[0], YS[1]); \
      uy.p[1] = __builtin_amdgcn_cvt_pkrtz(YS[2], YS[3]); \
      uy.p[2] = __builtin_amdgcn_cvt_pkrtz(YS[4], YS[5]); \
      uy.p[3] = __builtin_amdgcn_cvt_pkrtz(YS[6], YS[7]); \
      f16x8 fX = ux.v, fY = uy.v; \
      f16x8 fS = fX + fY, fD = fX - fY;      /* v_pk_add/sub_f16 */ \
      f16x8 fP = fS * fS, fM = fD * fD;      /* v_pk_mul_f16 */ \
      f32x4 dX = __builtin_amdgcn_mfma_f32_16x16x32_f16(fX, band_f, z, 0, 0, 0); \
      f32x4 dY = __builtin_amdgcn_mfma_f32_16x16x32_f16(fY, band_f, z, 0, 0, 0); \
      f32x4 dP = __builtin_amdgcn_mfma_f32_16x16x32_f16(fP, band_f, z, 0, 0, 0); \
      f32x4 dM = __builtin_amdgcn_mfma_f32_16x16x32_f16(fM, band_f, z, 0, 0, 0); \
      const int cb_ = (wv*4 + (T))*16 + kg*4; \
      VSTORE(0, dX) VSTORE(1, dY) VSTORE(2, dP) VSTORE(3, dM) }

    VPROC(0, xA, yA)
    VLOAD(2, xA, yA)
    VPROC(1, xB, yB)
    VLOAD(3, xB, yB)
    VPROC(2, xA, yA)
    VPROC(3, xB, yB)

    __syncthreads();     // the only inter-phase barrier

    // ---- H phase: A-frag = vlds[f][fi][c0+kB..+7] (one b128/field) ----
#define HPROC(T) \
    { const int c0_ = (wv*4 + (T))*16; \
      const int kb_ = min(c0_ + kB, IMG - 8); \
      f16x8 aX = *reinterpret_cast<const f16x8*>(&vlds[0][fi][kb_]); \
      f16x8 aY = *reinterpret_cast<const f16x8*>(&vlds[1][fi][kb_]); \
      f16x8 aP = *reinterpret_cast<const f16x8*>(&vlds[2][fi][kb_]); \
      f16x8 aM = *reinterpret_cast<const f16x8*>(&vlds[3][fi][kb_]); \
      f32x4 dX = __builtin_amdgcn_mfma_f32_16x16x32_f16(aX, band_f, z, 0, 0, 0); \
      f32x4 dY = __builtin_amdgcn_mfma_f32_16x16x32_f16(aY, band_f, z, 0, 0, 0); \
      f32x4 dP = __builtin_amdgcn_mfma_f32_16x16x32_f16(aP, band_f, z, 0, 0, 0); \
      f32x4 dM = __builtin_amdgcn_mfma_f32_16x16x32_f16(aM, band_f, z, 0, 0, 0); \
      const int oc = c0_ + fi; \
      if (oc < OUT_N) { \
          if (!edge) { \
              v2f mx0 = {dX[0], dX[1]}, my0 = {dY[0], dY[1]}; \
              v2f P0  = {dP[0], dP[1]}, M0  = {dM[0], dM[1]}; \
              v2f mx1 = {dX[2], dX[3]}, my1 = {dY[2], dY[3]}; \
              v2f P1  = {dP[2], dP[3]}, M1  = {dM[2], dM[3]}; \
              acc += ssim_px2(mx0, my0, P0, M0); \
              acc += ssim_px2(mx1, my1, P1, M1); \
          } else { \
              _Pragma("unroll") \
              for (int m = 0; m < 4; ++m) { \
                  const int oy = r0 + kg*4 + m; \
                  if (oy < OUT_N) \
                      acc += ssim_px(dX[m], dY[m], dP[m], dM[m]); \
              } \
          } } }

    HPROC(0) HPROC(1) HPROC(2) HPROC(3)

    // block reduction: wave shuffle, then 8 wave-partials through LDS
    #pragma unroll
    for (int off = 32; off > 0; off >>= 1)
        acc += __shfl_down(acc, off, 64);
    if (lane == 0) red[wv] = acc;
    __syncthreads();
    if (tid == 0) {
        float t = 0.f;
        #pragma unroll
        for (int i = 0; i < 8; ++i) t += red[i];
        partial[s] = t;
    }
}

// Deterministic final reduction: fixed traversal, double accumulation.
__global__ __launch_bounds__(256) void ssim_final(
    const float* __restrict__ partial, int n, float* __restrict__ out)
{
    __shared__ double red[256];
    double s = 0.0;
    for (int i = threadIdx.x; i < n; i += 256) s += (double)partial[i];
    red[threadIdx.x] = s;
    __syncthreads();
    for (int off = 128; off > 0; off >>= 1) {
        if (threadIdx.x < off) red[threadIdx.x] += red[threadIdx.x + off];
        __syncthreads();
    }
    if (threadIdx.x == 0) out[0] = (float)(1.0 - red[0] / (double)NPLANE);
}

extern "C" void kernel_launch(void* const* d_in, const int* in_sizes, int n_in,
                              void* d_out, int out_size, void* d_ws, size_t ws_size,
                              hipStream_t stream) {
    const float* in  = (const float*)d_in[0];
    const float* tgt = (const float*)d_in[1];
    const float* wt  = (const float*)d_in[2];
    float* out  = (float*)d_out;
    float* part = (float*)d_ws;

    ssim_band<<<dim3(NBLK), 512, 0, stream>>>(in, tgt, wt, part);
    ssim_final<<<1, 256, 0, stream>>>(part, NBLK, out);
}